// Round 2
// baseline (25.292 us; speedup 1.0000x reference)
//
#include <hip/hip_runtime.h>
#include <hip/hip_bf16.h>

#define MODEL_DIM 2048
#define F4_PER_ROW (MODEL_DIM / 4)   // 512
#define TOKENS_PER_BLOCK 4

__device__ __forceinline__ float4 qscale(float4 v, float s) {
    float4 r;
    // jnp.round == round-half-to-even == rintf (default rounding mode)
    r.x = fminf(fmaxf(rintf(v.x), -128.0f), 127.0f) * s;
    r.y = fminf(fmaxf(rintf(v.y), -128.0f), 127.0f) * s;
    r.z = fminf(fmaxf(rintf(v.z), -128.0f), 127.0f) * s;
    r.w = fminf(fmaxf(rintf(v.w), -128.0f), 127.0f) * s;
    return r;
}

__global__ __launch_bounds__(256) void qembed_gather4_kernel(
    const float* __restrict__ weights,  // [VOCAB, MODEL_DIM]
    const float* __restrict__ scales,   // [VOCAB]
    const int*   __restrict__ tokens,   // [N_TOKENS]
    float* __restrict__ out,            // [N_TOKENS, MODEL_DIM]
    int n_tokens)
{
    const int base = blockIdx.x * TOKENS_PER_BLOCK;
    const int tid  = threadIdx.x;

    if (base + TOKENS_PER_BLOCK <= n_tokens) {
        // Fast path: 4 independent token chains, hoisted.
        const int tk0 = tokens[base + 0];
        const int tk1 = tokens[base + 1];
        const int tk2 = tokens[base + 2];
        const int tk3 = tokens[base + 3];
        const float s0 = scales[tk0];
        const float s1 = scales[tk1];
        const float s2 = scales[tk2];
        const float s3 = scales[tk3];

        const float4* __restrict__ w0 = (const float4*)(weights + (size_t)tk0 * MODEL_DIM);
        const float4* __restrict__ w1 = (const float4*)(weights + (size_t)tk1 * MODEL_DIM);
        const float4* __restrict__ w2 = (const float4*)(weights + (size_t)tk2 * MODEL_DIM);
        const float4* __restrict__ w3 = (const float4*)(weights + (size_t)tk3 * MODEL_DIM);

        // 8 independent loads in flight per thread before any store.
        float4 a0 = w0[tid], a1 = w0[tid + 256];
        float4 b0 = w1[tid], b1 = w1[tid + 256];
        float4 c0 = w2[tid], c1 = w2[tid + 256];
        float4 d0 = w3[tid], d1 = w3[tid + 256];

        float4* __restrict__ o0 = (float4*)(out + (size_t)(base + 0) * MODEL_DIM);
        float4* __restrict__ o1 = (float4*)(out + (size_t)(base + 1) * MODEL_DIM);
        float4* __restrict__ o2 = (float4*)(out + (size_t)(base + 2) * MODEL_DIM);
        float4* __restrict__ o3 = (float4*)(out + (size_t)(base + 3) * MODEL_DIM);

        o0[tid] = qscale(a0, s0); o0[tid + 256] = qscale(a1, s0);
        o1[tid] = qscale(b0, s1); o1[tid + 256] = qscale(b1, s1);
        o2[tid] = qscale(c0, s2); o2[tid + 256] = qscale(c1, s2);
        o3[tid] = qscale(d0, s3); o3[tid + 256] = qscale(d1, s3);
    } else {
        // Tail path (not hit for n_tokens % 4 == 0).
        for (int j = 0; j < TOKENS_PER_BLOCK; ++j) {
            const int t = base + j;
            if (t >= n_tokens) break;
            const int tok = tokens[t];
            const float s = scales[tok];
            const float4* __restrict__ wrow = (const float4*)(weights + (size_t)tok * MODEL_DIM);
            float4* __restrict__ orow = (float4*)(out + (size_t)t * MODEL_DIM);
            for (int i = tid; i < F4_PER_ROW; i += 256)
                orow[i] = qscale(wrow[i], s);
        }
    }
}

extern "C" void kernel_launch(void* const* d_in, const int* in_sizes, int n_in,
                              void* d_out, int out_size, void* d_ws, size_t ws_size,
                              hipStream_t stream) {
    const float* weights = (const float*)d_in[0];
    const float* scales  = (const float*)d_in[1];
    const int*   tokens  = (const int*)d_in[2];
    float* out = (float*)d_out;

    const int n_tokens = in_sizes[2];  // 8192
    const int blocks = (n_tokens + TOKENS_PER_BLOCK - 1) / TOKENS_PER_BLOCK;

    qembed_gather4_kernel<<<blocks, 256, 0, stream>>>(weights, scales, tokens, out, n_tokens);
}